// Round 9
// baseline (515.685 us; speedup 1.0000x reference)
//
#include <hip/hip_runtime.h>
#include <hip/hip_bf16.h>
#include <math.h>

#define B 16
#define NN 50
#define D 400
#define H 20
#define DH 20
#define ATT_H 128
#define NEWS 20000
#define K 10
#define STEPS 6
#define SLOTS 10
#define L 500
#define EPS 1e-5f

#define XP 416            // padded K-dim (13 * 32), bf16 row stride for x and wT
#define NC 1200           // q|k|v concatenated N
#define WTB 75            // 3 * 25 transpose tiles (16 cols each)

typedef short short4v __attribute__((ext_vector_type(4)));
typedef short short8 __attribute__((ext_vector_type(8)));
typedef float floatx4 __attribute__((ext_vector_type(4)));
typedef float floatx2 __attribute__((ext_vector_type(2)));

__device__ __forceinline__ short f2bf(float f) {
    __hip_bfloat16 h = __float2bfloat16(f);
    return *reinterpret_cast<short*>(&h);
}

// ---------- Kernel 1: traversal + weight transpose fused (independent work) --
// blocks 0..799: per-item 6-hop traversal -> x bf16 [B*L][XP]
// blocks 800..874: LDS-tiled W^T | concat + bf16 (coalesced both sides)
__global__ __launch_bounds__(256) void k_prep(
    const float* __restrict__ news,   // [B,NN,D]
    const float* __restrict__ table,  // [NEWS,K,D]
    const int*   __restrict__ click,  // [B,NN]
    const int*   __restrict__ nbrt,   // [NEWS+1,K]
    const float* __restrict__ Wq, const float* __restrict__ Wk,
    const float* __restrict__ Wv,
    short* __restrict__ x,            // [B*L][XP] bf16
    short* __restrict__ wT)           // [NC][XP] bf16
{
    __shared__ float ssc[K];
    __shared__ int   snbr[K];

    int blk = blockIdx.x;
    int tid = threadIdx.x;

    if (blk >= B * NN) {              // ---- weight transpose, LDS-tiled ----
        __shared__ float wtile[16][401];   // 401 ≡ 17 (mod 32): conflict-free
        int blk2 = blk - B * NN;      // 0..74
        int z = blk2 / 25, nt = blk2 % 25;
        int n0 = nt * 16;
        const float* W = (z == 0) ? Wq : (z == 1) ? Wk : Wv;
        float sc = (z == 0) ? 0.22360679774997896f : 1.0f;  // fold 1/sqrt(20) into Wq
        int kk = tid >> 4, noff = tid & 15;
        for (int k0 = 0; k0 < 400; k0 += 16)               // coalesced 64-B reads
            wtile[noff][k0 + kk] = W[(size_t)(k0 + kk) * 400 + n0 + noff];
        __syncthreads();
        int c0 = z * 400 + n0;
        for (int r = 0; r < 16; r++) {                     // coalesced row writes
            short* dst = wT + (size_t)(c0 + r) * XP;
            dst[tid] = f2bf(wtile[r][tid] * sc);           // tid < 256 < 400
            int c2 = tid + 256;
            if (c2 < XP) dst[c2] = (c2 < 400) ? f2bf(wtile[r][c2] * sc) : (short)0;
        }
        return;
    }

    int item = blk;                   // 0..799
    int b = item / NN, n = item % NN;
    int lane = tid & 63, w = tid >> 6;

    float nv[7];
    bool nzf = false;
    #pragma unroll
    for (int i = 0; i < 7; i++) {
        int d = lane + 64 * i;
        float v = (d < D) ? news[(size_t)item * D + d] : 0.0f;
        nv[i] = v;
        nzf |= (v != 0.0f);
    }
    float valid = __any(nzf) ? 1.0f : 0.0f;

    int idx = click[item];
    bool dead = false;
    short* xbase = x + (size_t)(b * L + n * SLOTS) * XP;

    for (int step = 0; step < STEPS; step++) {
        const float* tb = table + (size_t)(idx - 1) * K * D;
        if (tid < K) snbr[tid] = nbrt[(size_t)idx * K + tid];   // prefetch neighbors
        for (int kk = w; kk < K; kk += 4) {
            float p = 0.0f;
            #pragma unroll
            for (int i = 0; i < 7; i++) {
                int d = lane + 64 * i;
                if (d < D) p += tb[kk * D + d] * nv[i];
            }
            #pragma unroll
            for (int off = 32; off > 0; off >>= 1) p += __shfl_xor(p, off);
            if (lane == 0) ssc[kk] = p;
        }
        __syncthreads();

        float scores[K];
        #pragma unroll
        for (int kk = 0; kk < K; kk++) scores[kk] = ssc[kk];

        int mx_i = 0; float mx_v = scores[0];
        #pragma unroll
        for (int kk = 1; kk < K; kk++)
            if (scores[kk] > mx_v) { mx_v = scores[kk]; mx_i = kk; }

        bool any_nz = false; int nz_i = 0; float nz_v = -INFINITY;
        #pragma unroll
        for (int kk = 0; kk < K; kk++) {
            if (scores[kk] != 0.0f) {
                if (!any_nz || scores[kk] > nz_v) { nz_v = scores[kk]; nz_i = kk; }
                any_nz = true;
            }
        }

        bool hop = (mx_v == 0.0f) && !dead;
        int sel_i = (hop && any_nz) ? nz_i : mx_i;
        bool new_dead = dead || (hop && !any_nz);
        int nbr = snbr[sel_i];
        int new_idx = (hop && any_nz) ? nbr : idx;

        float scale = new_dead ? 0.0f : valid;
        const float* selrow = tb + (size_t)sel_i * D;   // 1600-B aligned
        short* xr = xbase + (size_t)step * XP;          // 832-B aligned rows
        for (int d2 = tid; d2 < XP / 2; d2 += 256) {    // packed 2-short stores
            int d = d2 * 2;
            int pr = 0;
            if (d < D) {
                floatx2 fv = *(const floatx2*)&selrow[d];
                int lo = f2bf(fv[0] * scale) & 0xffff;
                int hi = f2bf(fv[1] * scale) & 0xffff;
                pr = lo | (hi << 16);
            }
            *(int*)&xr[d] = pr;
        }

        idx = new_idx; dead = new_dead;
        __syncthreads();
    }
    for (int s = STEPS; s < SLOTS; s++) {               // int4 zero fill
        short* xr = xbase + (size_t)s * XP;
        for (int d8 = tid; d8 < XP / 8; d8 += 256) {
            int4 z = {0, 0, 0, 0};
            *(int4*)&xr[d8 * 8] = z;
        }
    }
}

// -------------------- Kernel 2: fused QKV GEMM via bf16 MFMA ----------------
// 128x128 tile (m93-class): 2x2 wave grid, 4x4 16x16 frags per wave.
#define BM 128
#define BN 128
#define BKK 32

__global__ __launch_bounds__(256) void k_qkv_mfma(
    const short* __restrict__ xg,      // [8000][XP] bf16
    const short* __restrict__ wT,      // [1200][XP] bf16
    short* __restrict__ c)             // [8000][1200] bf16
{
    __shared__ short xs[BM][BKK + 8];
    __shared__ short wt[BN][BKK + 8];

    int tid = threadIdx.x;
    int m0 = blockIdx.x * BM;
    int n0 = blockIdx.y * BN;
    int lane = tid & 63, w = tid >> 6;
    int wr = w >> 1, wc = w & 1;
    int quad = lane >> 4, l16 = lane & 15;

    floatx4 acc[4][4];
    #pragma unroll
    for (int i = 0; i < 4; i++)
        #pragma unroll
        for (int j = 0; j < 4; j++) acc[i][j] = (floatx4){0.f, 0.f, 0.f, 0.f};

    int xr = tid >> 1, xc = (tid & 1) * 16;   // row 0..127, col 0/16
    bool xok = (m0 + xr) < 8000;
    bool wok = (n0 + xr) < NC;

    for (int k0 = 0; k0 < XP; k0 += BKK) {
        int4 xv0 = {0,0,0,0}, xv1 = {0,0,0,0}, wv0 = {0,0,0,0}, wv1 = {0,0,0,0};
        if (xok) {
            const int4* src = (const int4*)(xg + (size_t)(m0 + xr) * XP + k0 + xc);
            xv0 = src[0]; xv1 = src[1];
        }
        if (wok) {
            const int4* src = (const int4*)(wT + (size_t)(n0 + xr) * XP + k0 + xc);
            wv0 = src[0]; wv1 = src[1];
        }
        __syncthreads();
        *(int4*)&xs[xr][xc]     = xv0;
        *(int4*)&xs[xr][xc + 8] = xv1;
        *(int4*)&wt[xr][xc]     = wv0;
        *(int4*)&wt[xr][xc + 8] = wv1;
        __syncthreads();

        short8 a[4], bf[4];
        #pragma unroll
        for (int fi = 0; fi < 4; fi++)
            a[fi] = *(const short8*)&xs[wr * 64 + fi * 16 + l16][quad * 8];
        #pragma unroll
        for (int fj = 0; fj < 4; fj++)
            bf[fj] = *(const short8*)&wt[wc * 64 + fj * 16 + l16][quad * 8];
        #pragma unroll
        for (int fi = 0; fi < 4; fi++)
            #pragma unroll
            for (int fj = 0; fj < 4; fj++)
                acc[fi][fj] = __builtin_amdgcn_mfma_f32_16x16x32_bf16(
                    a[fi], bf[fj], acc[fi][fj], 0, 0, 0);
    }

    #pragma unroll
    for (int fi = 0; fi < 4; fi++) {
        int grow_base = m0 + wr * 64 + fi * 16 + quad * 4;
        #pragma unroll
        for (int fj = 0; fj < 4; fj++) {
            int gcol = n0 + wc * 64 + fj * 16 + l16;
            #pragma unroll
            for (int r = 0; r < 4; r++) {
                int grow = grow_base + r;
                if (grow < 8000 && gcol < NC)
                    c[(size_t)grow * NC + gcol] = f2bf(acc[fi][fj][r]);
            }
        }
    }
}

// -------------------- Kernel 3: MFMA flash attention (swapped-operand) ------
// S^T = mfma(K, Q): lane owns one q-row (col=l16) and 8 j-values. Row-max =
// 7 lane-local fmax + 2 shuffle stages. Softmax denominator accumulates as a
// ones-row (d=20) of V^T through the PV MFMA (no sum-reduce).
#define KSTR 24
#define VSTR 520
#define PSTR 40
#define QSPLIT 2

__global__ __launch_bounds__(256) void k_attn4(
    const short* __restrict__ qkv,   // [8000][1200] bf16 = q|k|v
    const int* __restrict__ mask,    // [B,L]
    float* __restrict__ o)           // [8000][400]
{
    // Ksh [512][24] @0 ; VT [21][520] ; P [4][16][40] ; msk [512] bf16
    __shared__ short sh[12288 + 21 * VSTR + 4 * 16 * PSTR + 512];  // 52560 B
    short* VTb = sh + 12288;
    short* Pb  = VTb + 21 * VSTR;
    short* msk = Pb + 4 * 16 * PSTR;

    int part = blockIdx.x & (QSPLIT - 1);
    int bh = blockIdx.x >> 1;
    int b = bh / H, h = bh % H;
    int tid = threadIdx.x;
    int lane = tid & 63, w = tid >> 6;
    int quad = lane >> 4, l16 = lane & 15;

    // ---- stage K bf16 [512][24] via int loads: 12 short2 per row ----
    for (int u = tid; u < 512 * (KSTR / 2); u += 256) {
        int j = u / (KSTR / 2), t = u % (KSTR / 2);
        int v = 0;
        if (j < L && t < DH / 2)
            v = *(const int*)(qkv + (size_t)(b * L + j) * NC + 400 + h * DH + 2 * t);
        *(int*)&sh[j * KSTR + 2 * t] = v;
    }
    // ---- stage V^T rows 0..19: int load (d=2t,2t+1), two scalar LDS writes --
    for (int u = tid; u < L * (DH / 2); u += 256) {
        int j = u / (DH / 2), t = u % (DH / 2);
        int v = *(const int*)(qkv + (size_t)(b * L + j) * NC + 800 + h * DH + 2 * t);
        VTb[(2 * t) * VSTR + j]     = (short)(v & 0xffff);
        VTb[(2 * t + 1) * VSTR + j] = (short)((unsigned)v >> 16);
    }
    // ---- ones row d=20 (denominator trick) + bf16 mask; tails zeroed ----
    for (int j = tid; j < 512; j += 256) {
        VTb[20 * VSTR + j] = (j < L) ? f2bf(1.0f) : (short)0;
        msk[j] = (j < L && mask[(size_t)b * L + j] > 0) ? f2bf(1.0f) : (short)0;
    }
    for (int i = tid; i < DH * 12; i += 256) {   // zero V j-tail 500..511
        int d = i / 12, j = L + i % 12;
        VTb[d * VSTR + j] = 0;
    }
    __syncthreads();

    short* Pw = Pb + w * 16 * PSTR;       // per-wave private P^T buffer [16 q][32 j]
    short* pwr = Pw + l16 * PSTR;         // this lane's q-row
    const short* prd = Pw + l16 * PSTR + quad * 8;   // B-frag read base (16B-aligned)
    const short* kA  = sh + quad * 8;     // K A-frag col base (quad<3 only)
    const short* vA0 = VTb + l16 * VSTR;              // V^T rows 0..15
    int r1 = 16 + l16; if (r1 > 20) r1 = 20;          // clamp: garbage rows ignored
    const short* vA1 = VTb + r1 * VSTR;

    for (int qt = part * 16 + w; qt < part * 16 + 16; qt += 4) {
        // Q B-frag: 8-B short4 loads (base = 2400*row + 40h bytes, 8-B aligned)
        int qrow = qt * 16 + l16;
        const short* qp = qkv + (size_t)(b * L + (qrow < L ? qrow : 0)) * NC + h * DH;
        short8 aq = (short8)(short)0;
        if (quad < 2) {
            short4v a0 = *(const short4v*)(qp + quad * 8);
            short4v a1 = *(const short4v*)(qp + quad * 8 + 4);
            #pragma unroll
            for (int jj = 0; jj < 4; jj++) { aq[jj] = a0[jj]; aq[4 + jj] = a1[jj]; }
        } else if (quad == 2) {
            short4v a0 = *(const short4v*)(qp + 16);   // k = 16..19 valid
            #pragma unroll
            for (int jj = 0; jj < 4; jj++) aq[jj] = a0[jj];
        }
        // q-rows >= L read row 0: finite garbage, never stored (guard below)

        floatx4 O0 = (floatx4){0.f,0.f,0.f,0.f};
        floatx4 O1 = (floatx4){0.f,0.f,0.f,0.f};
        float mrun = -INFINITY;

        for (int jt = 0; jt < 16; jt++) {
            // K A-frags (quad3 -> zero regs; quad<3 reads [quad*8..+8) of 24-col rows)
            short8 ak0 = (short8)(short)0, ak1 = (short8)(short)0;
            if (quad < 3) {
                ak0 = *(const short8*)&kA[(jt * 32 + l16) * KSTR];
                ak1 = *(const short8*)&kA[(jt * 32 + 16 + l16) * KSTR];
            }
            floatx4 z = (floatx4){0.f,0.f,0.f,0.f};
            // S^T[j,q]: col=l16=q, row=quad*4+r=j (half0 / half1)
            floatx4 s0 = __builtin_amdgcn_mfma_f32_16x16x32_bf16(ak0, aq, z, 0, 0, 0);
            floatx4 s1 = __builtin_amdgcn_mfma_f32_16x16x32_bf16(ak1, aq, z, 0, 0, 0);

            short4v mk0 = *(const short4v*)&msk[jt * 32 + quad * 4];
            short4v mk1 = *(const short4v*)&msk[jt * 32 + 16 + quad * 4];
            #pragma unroll
            for (int r = 0; r < 4; r++) {
                s0[r] = (mk0[r] != 0) ? s0[r] : -1e9f;
                s1[r] = (mk1[r] != 0) ? s1[r] : -1e9f;
            }

            // tile row-max: 7 lane-local max + 2 cross-quad stages
            float mt = fmaxf(fmaxf(fmaxf(s0[0], s0[1]), fmaxf(s0[2], s0[3])),
                             fmaxf(fmaxf(s1[0], s1[1]), fmaxf(s1[2], s1[3])));
            mt = fmaxf(mt, __shfl_xor(mt, 16));
            mt = fmaxf(mt, __shfl_xor(mt, 32));

            if (!__all(mt <= mrun)) {
                float mnew = fmaxf(mrun, mt);
                float alpha = __expf(mrun - mnew);
                mrun = mnew;
                #pragma unroll
                for (int r = 0; r < 4; r++) { O0[r] *= alpha; O1[r] *= alpha; }
            }

            // P = exp(S - m); denominator accumulates via ones-row of V^T
            short4v pk0, pk1;
            #pragma unroll
            for (int r = 0; r < 4; r++) {
                pk0[r] = f2bf(__expf(s0[r] - mrun));
                pk1[r] = f2bf(__expf(s1[r] - mrun));
            }
            *(short4v*)&pwr[quad * 4]      = pk0;   // j = quad*4+r   (half 0)
            *(short4v*)&pwr[16 + quad * 4] = pk1;   // j = 16+quad*4+r (half 1)

            short8 ap  = *(const short8*)prd;                       // P^T B-frag
            short8 va0 = *(const short8*)&vA0[jt * 32 + quad * 8];  // V^T A-frag d=0..15
            short8 va1 = *(const short8*)&vA1[jt * 32 + quad * 8];  // d=16..20 (clamped)
            O0 = __builtin_amdgcn_mfma_f32_16x16x32_bf16(va0, ap, O0, 0, 0, 0);
            O1 = __builtin_amdgcn_mfma_f32_16x16x32_bf16(va1, ap, O1, 0, 0, 0);
        }

        // denominator lives at O^T row 20 = quad1, reg 0; broadcast per q-col
        float lsum = __shfl(O1[0], 16 + l16);
        float inv = 1.0f / lsum;
        int q = qt * 16 + l16;
        if (q < L) {
            float* op = o + (size_t)(b * L + q) * (H * DH) + h * DH;
            floatx4 v0;
            #pragma unroll
            for (int r = 0; r < 4; r++) v0[r] = O0[r] * inv;
            *(floatx4*)&op[quad * 4] = v0;           // d = quad*4..+3
            if (quad == 0) {
                floatx4 v1;
                #pragma unroll
                for (int r = 0; r < 4; r++) v1[r] = O1[r] * inv;
                *(floatx4*)&op[16] = v1;             // d = 16..19
            }
        }
    }
}

// -------------------- Kernel 4: LN1 + att_pool + LN2, 2 groups/block --------
// fc1w (410 KB incl. 2x duplication) is read once per block from L2 but now
// serves TWO groups -> L2 traffic halved. Per-(group,slot,jh) accumulation
// order over d is unchanged -> bit-identical results.
__global__ __launch_bounds__(256) void k_pool(
    const float* __restrict__ o,
    const float* __restrict__ ln1g, const float* __restrict__ ln1b,
    const float* __restrict__ fc1w, const float* __restrict__ fc1b,
    const float* __restrict__ fc2w, const float* __restrict__ fc2b,
    const float* __restrict__ ln2g, const float* __restrict__ ln2b,
    const int* __restrict__ mask,   // [800,10]
    float* __restrict__ out)        // [800,400]
{
    __shared__ float xt[2 * SLOTS][D];      // 32 KB
    __shared__ float hv[2 * SLOTS * ATT_H]; // 10.25 KB
    __shared__ float es[2 * SLOTS];
    __shared__ float red[2][8];

    int g0 = blockIdx.x * 2;
    int tid = threadIdx.x;
    int lane = tid & 63, w = tid >> 6;

    const float* xg = o + (size_t)g0 * SLOTS * D;   // 20 contiguous rows

    for (int s = w; s < 2 * SLOTS; s += 4) {
        const float* xr = xg + (size_t)s * D;
        float vbuf[7];
        float sum = 0.0f, sq = 0.0f;
        #pragma unroll
        for (int i = 0; i < 7; i++) {
            int d = lane + 64 * i;
            float v = (d < D) ? xr[d] : 0.0f;
            vbuf[i] = v; sum += v; sq += v * v;
        }
        #pragma unroll
        for (int off = 32; off > 0; off >>= 1) {
            sum += __shfl_xor(sum, off);
            sq  += __shfl_xor(sq, off);
        }
        float mean = sum / (float)D;
        float var = sq / (float)D - mean * mean;
        float rs = rsqrtf(var + EPS);
        #pragma unroll
        for (int i = 0; i < 7; i++) {
            int d = lane + 64 * i;
            if (d < D) xt[s][d] = (vbuf[i] - mean) * rs * ln1g[d] + ln1b[d];
        }
    }
    __syncthreads();

    {
        // fc1: thread handles all 10 slots of ONE group (grp = tid>>7)
        int jh = tid & 127;
        int grp = tid >> 7;
        float hs[SLOTS];
        #pragma unroll
        for (int s = 0; s < SLOTS; s++) hs[s] = fc1b[jh];
        for (int d = 0; d < D; d += 4) {
            floatx4 xv[SLOTS];
            #pragma unroll
            for (int s = 0; s < SLOTS; s++)
                xv[s] = *(const floatx4*)&xt[grp * SLOTS + s][d];
            #pragma unroll
            for (int dd = 0; dd < 4; dd++) {
                float fw = fc1w[(size_t)(d + dd) * ATT_H + jh];
                #pragma unroll
                for (int s = 0; s < SLOTS; s++) hs[s] += xv[s][dd] * fw;
            }
        }
        float f2 = fc2w[jh];
        #pragma unroll
        for (int s = 0; s < SLOTS; s++)
            hv[(grp * SLOTS + s) * ATT_H + jh] = tanhf(hs[s]) * f2;
    }
    __syncthreads();

    for (int s = w; s < 2 * SLOTS; s += 4) {
        float p = hv[s * ATT_H + lane] + hv[s * ATT_H + lane + 64];
        #pragma unroll
        for (int off = 32; off > 0; off >>= 1) p += __shfl_xor(p, off);
        if (lane == 0) es[s] = p + fc2b[0];
    }
    __syncthreads();

    for (int g = 0; g < 2; g++) {
        float ev[SLOTS];
        float emax = -INFINITY;
        #pragma unroll
        for (int s = 0; s < SLOTS; s++) {
            float e = (mask[(size_t)(g0 + g) * SLOTS + s] > 0) ? es[g * SLOTS + s] : -1e9f;
            ev[s] = e;
            if (e > emax) emax = e;
        }
        float esum = 0.0f;
        #pragma unroll
        for (int s = 0; s < SLOTS; s++) { ev[s] = __expf(ev[s] - emax); esum += ev[s]; }
        float einv = 1.0f / esum;

        int d0 = tid, d1 = tid + 256;
        float p0 = 0.0f, p1 = 0.0f;
        #pragma unroll
        for (int s = 0; s < SLOTS; s++) {
            p0 += ev[s] * xt[g * SLOTS + s][d0];
            if (d1 < D) p1 += ev[s] * xt[g * SLOTS + s][d1];
        }
        p0 *= einv; p1 *= einv;

        float sum = p0 + ((d1 < D) ? p1 : 0.0f);
        float sq  = p0 * p0 + ((d1 < D) ? p1 * p1 : 0.0f);
        #pragma unroll
        for (int off = 32; off > 0; off >>= 1) {
            sum += __shfl_xor(sum, off);
            sq  += __shfl_xor(sq, off);
        }
        if (lane == 0) { red[g][w] = sum; red[g][4 + w] = sq; }
        __syncthreads();
        float tsum = red[g][0] + red[g][1] + red[g][2] + red[g][3];
        float tsq  = red[g][4] + red[g][5] + red[g][6] + red[g][7];
        float mean = tsum / (float)D;
        float var = tsq / (float)D - mean * mean;
        float rs = rsqrtf(var + EPS);

        float* og = out + (size_t)(g0 + g) * D;
        og[d0] = (p0 - mean) * rs * ln2g[d0] + ln2b[d0];
        if (d1 < D) og[d1] = (p1 - mean) * rs * ln2g[d1] + ln2b[d1];
    }
}

extern "C" void kernel_launch(void* const* d_in, const int* in_sizes, int n_in,
                              void* d_out, int out_size, void* d_ws, size_t ws_size,
                              hipStream_t stream) {
    const float* news  = (const float*)d_in[0];
    const float* table = (const float*)d_in[1];
    const float* Wq    = (const float*)d_in[2];
    const float* Wk    = (const float*)d_in[3];
    const float* Wv    = (const float*)d_in[4];
    const float* ln1g  = (const float*)d_in[5];
    const float* ln1b  = (const float*)d_in[6];
    const float* fc1w  = (const float*)d_in[7];
    const float* fc1b  = (const float*)d_in[8];
    const float* fc2w  = (const float*)d_in[9];
    const float* fc2b  = (const float*)d_in[10];
    const float* ln2g  = (const float*)d_in[11];
    const float* ln2b  = (const float*)d_in[12];
    const int* click   = (const int*)d_in[13];
    const int* nbrt    = (const int*)d_in[14];
    const int* mask    = (const int*)d_in[15];
    float* out = (float*)d_out;

    char* p = (char*)d_ws;
    short* xbf = (short*)p;  p += (size_t)8000 * XP * sizeof(short);   // 6.656 MB
    short* wT  = (short*)p;  p += (size_t)NC * XP * sizeof(short);     // 1.0 MB
    short* qkv = (short*)p;  p += (size_t)8000 * NC * sizeof(short);   // 19.2 MB
    float* ob  = (float*)p;                                            // 12.8 MB

    k_prep<<<dim3(B * NN + WTB), dim3(256), 0, stream>>>(
        news, table, click, nbrt, Wq, Wk, Wv, xbf, wT);
    k_qkv_mfma<<<dim3((8000 + BM - 1) / BM, (NC + BN - 1) / BN), dim3(256), 0, stream>>>(
        xbf, wT, qkv);
    k_attn4<<<dim3(B * H * QSPLIT), dim3(256), 0, stream>>>(qkv, mask, ob);
    k_pool<<<dim3(B * NN / 2), dim3(256), 0, stream>>>(ob, ln1g, ln1b, fc1w, fc1b,
                                                       fc2w, fc2b, ln2g, ln2b, mask, out);
}

// Round 10
// 509.131 us; speedup vs baseline: 1.0129x; 1.0129x over previous
//
#include <hip/hip_runtime.h>
#include <hip/hip_bf16.h>
#include <math.h>

#define B 16
#define NN 50
#define D 400
#define H 20
#define DH 20
#define ATT_H 128
#define NEWS 20000
#define K 10
#define STEPS 6
#define SLOTS 10
#define L 500
#define EPS 1e-5f

#define XP 416            // padded K-dim (13 * 32), bf16 row stride for x and wT
#define NC 1200           // q|k|v concatenated N
#define WTB 75            // 3 * 25 transpose tiles (16 cols each)

typedef short short4v __attribute__((ext_vector_type(4)));
typedef short short8 __attribute__((ext_vector_type(8)));
typedef float floatx4 __attribute__((ext_vector_type(4)));
typedef float floatx2 __attribute__((ext_vector_type(2)));

__device__ __forceinline__ short f2bf(float f) {
    __hip_bfloat16 h = __float2bfloat16(f);
    return *reinterpret_cast<short*>(&h);
}

// ---------- Kernel 1: traversal + weight transpose fused (independent work) --
// blocks 0..799: per-item 6-hop traversal -> x bf16 [B*L][XP]
// blocks 800..874: LDS-tiled W^T | concat + bf16 (coalesced both sides)
__global__ __launch_bounds__(256) void k_prep(
    const float* __restrict__ news,   // [B,NN,D]
    const float* __restrict__ table,  // [NEWS,K,D]
    const int*   __restrict__ click,  // [B,NN]
    const int*   __restrict__ nbrt,   // [NEWS+1,K]
    const float* __restrict__ Wq, const float* __restrict__ Wk,
    const float* __restrict__ Wv,
    short* __restrict__ x,            // [B*L][XP] bf16
    short* __restrict__ wT)           // [NC][XP] bf16
{
    __shared__ float ssc[K];
    __shared__ int   snbr[K];

    int blk = blockIdx.x;
    int tid = threadIdx.x;

    if (blk >= B * NN) {              // ---- weight transpose, LDS-tiled ----
        __shared__ float wtile[16][401];   // 401 ≡ 17 (mod 32): conflict-free
        int blk2 = blk - B * NN;      // 0..74
        int z = blk2 / 25, nt = blk2 % 25;
        int n0 = nt * 16;
        const float* W = (z == 0) ? Wq : (z == 1) ? Wk : Wv;
        float sc = (z == 0) ? 0.22360679774997896f : 1.0f;  // fold 1/sqrt(20) into Wq
        int kk = tid >> 4, noff = tid & 15;
        for (int k0 = 0; k0 < 400; k0 += 16)               // coalesced 64-B reads
            wtile[noff][k0 + kk] = W[(size_t)(k0 + kk) * 400 + n0 + noff];
        __syncthreads();
        int c0 = z * 400 + n0;
        for (int r = 0; r < 16; r++) {                     // coalesced row writes
            short* dst = wT + (size_t)(c0 + r) * XP;
            dst[tid] = f2bf(wtile[r][tid] * sc);           // tid < 256 < 400
            int c2 = tid + 256;
            if (c2 < XP) dst[c2] = (c2 < 400) ? f2bf(wtile[r][c2] * sc) : (short)0;
        }
        return;
    }

    int item = blk;                   // 0..799
    int b = item / NN, n = item % NN;
    int lane = tid & 63, w = tid >> 6;

    float nv[7];
    bool nzf = false;
    #pragma unroll
    for (int i = 0; i < 7; i++) {
        int d = lane + 64 * i;
        float v = (d < D) ? news[(size_t)item * D + d] : 0.0f;
        nv[i] = v;
        nzf |= (v != 0.0f);
    }
    float valid = __any(nzf) ? 1.0f : 0.0f;

    int idx = click[item];
    bool dead = false;
    short* xbase = x + (size_t)(b * L + n * SLOTS) * XP;

    for (int step = 0; step < STEPS; step++) {
        const float* tb = table + (size_t)(idx - 1) * K * D;
        if (tid < K) snbr[tid] = nbrt[(size_t)idx * K + tid];   // prefetch neighbors
        for (int kk = w; kk < K; kk += 4) {
            float p = 0.0f;
            #pragma unroll
            for (int i = 0; i < 7; i++) {
                int d = lane + 64 * i;
                if (d < D) p += tb[kk * D + d] * nv[i];
            }
            #pragma unroll
            for (int off = 32; off > 0; off >>= 1) p += __shfl_xor(p, off);
            if (lane == 0) ssc[kk] = p;
        }
        __syncthreads();

        float scores[K];
        #pragma unroll
        for (int kk = 0; kk < K; kk++) scores[kk] = ssc[kk];

        int mx_i = 0; float mx_v = scores[0];
        #pragma unroll
        for (int kk = 1; kk < K; kk++)
            if (scores[kk] > mx_v) { mx_v = scores[kk]; mx_i = kk; }

        bool any_nz = false; int nz_i = 0; float nz_v = -INFINITY;
        #pragma unroll
        for (int kk = 0; kk < K; kk++) {
            if (scores[kk] != 0.0f) {
                if (!any_nz || scores[kk] > nz_v) { nz_v = scores[kk]; nz_i = kk; }
                any_nz = true;
            }
        }

        bool hop = (mx_v == 0.0f) && !dead;
        int sel_i = (hop && any_nz) ? nz_i : mx_i;
        bool new_dead = dead || (hop && !any_nz);
        int nbr = snbr[sel_i];
        int new_idx = (hop && any_nz) ? nbr : idx;

        float scale = new_dead ? 0.0f : valid;
        const float* selrow = tb + (size_t)sel_i * D;   // 1600-B aligned
        short* xr = xbase + (size_t)step * XP;          // 832-B aligned rows
        for (int d2 = tid; d2 < XP / 2; d2 += 256) {    // packed 2-short stores
            int d = d2 * 2;
            int pr = 0;
            if (d < D) {
                floatx2 fv = *(const floatx2*)&selrow[d];
                int lo = f2bf(fv[0] * scale) & 0xffff;
                int hi = f2bf(fv[1] * scale) & 0xffff;
                pr = lo | (hi << 16);
            }
            *(int*)&xr[d] = pr;
        }

        idx = new_idx; dead = new_dead;
        __syncthreads();
    }
    for (int s = STEPS; s < SLOTS; s++) {               // int4 zero fill
        short* xr = xbase + (size_t)s * XP;
        for (int d8 = tid; d8 < XP / 8; d8 += 256) {
            int4 z = {0, 0, 0, 0};
            *(int4*)&xr[d8 * 8] = z;
        }
    }
}

// -------------------- Kernel 2: fused QKV GEMM via bf16 MFMA ----------------
// 128x128 tile (m93-class): 2x2 wave grid, 4x4 16x16 frags per wave.
#define BM 128
#define BN 128
#define BKK 32

__global__ __launch_bounds__(256) void k_qkv_mfma(
    const short* __restrict__ xg,      // [8000][XP] bf16
    const short* __restrict__ wT,      // [1200][XP] bf16
    short* __restrict__ c)             // [8000][1200] bf16
{
    __shared__ short xs[BM][BKK + 8];
    __shared__ short wt[BN][BKK + 8];

    int tid = threadIdx.x;
    int m0 = blockIdx.x * BM;
    int n0 = blockIdx.y * BN;
    int lane = tid & 63, w = tid >> 6;
    int wr = w >> 1, wc = w & 1;
    int quad = lane >> 4, l16 = lane & 15;

    floatx4 acc[4][4];
    #pragma unroll
    for (int i = 0; i < 4; i++)
        #pragma unroll
        for (int j = 0; j < 4; j++) acc[i][j] = (floatx4){0.f, 0.f, 0.f, 0.f};

    int xr = tid >> 1, xc = (tid & 1) * 16;   // row 0..127, col 0/16
    bool xok = (m0 + xr) < 8000;
    bool wok = (n0 + xr) < NC;

    for (int k0 = 0; k0 < XP; k0 += BKK) {
        int4 xv0 = {0,0,0,0}, xv1 = {0,0,0,0}, wv0 = {0,0,0,0}, wv1 = {0,0,0,0};
        if (xok) {
            const int4* src = (const int4*)(xg + (size_t)(m0 + xr) * XP + k0 + xc);
            xv0 = src[0]; xv1 = src[1];
        }
        if (wok) {
            const int4* src = (const int4*)(wT + (size_t)(n0 + xr) * XP + k0 + xc);
            wv0 = src[0]; wv1 = src[1];
        }
        __syncthreads();
        *(int4*)&xs[xr][xc]     = xv0;
        *(int4*)&xs[xr][xc + 8] = xv1;
        *(int4*)&wt[xr][xc]     = wv0;
        *(int4*)&wt[xr][xc + 8] = wv1;
        __syncthreads();

        short8 a[4], bf[4];
        #pragma unroll
        for (int fi = 0; fi < 4; fi++)
            a[fi] = *(const short8*)&xs[wr * 64 + fi * 16 + l16][quad * 8];
        #pragma unroll
        for (int fj = 0; fj < 4; fj++)
            bf[fj] = *(const short8*)&wt[wc * 64 + fj * 16 + l16][quad * 8];
        #pragma unroll
        for (int fi = 0; fi < 4; fi++)
            #pragma unroll
            for (int fj = 0; fj < 4; fj++)
                acc[fi][fj] = __builtin_amdgcn_mfma_f32_16x16x32_bf16(
                    a[fi], bf[fj], acc[fi][fj], 0, 0, 0);
    }

    #pragma unroll
    for (int fi = 0; fi < 4; fi++) {
        int grow_base = m0 + wr * 64 + fi * 16 + quad * 4;
        #pragma unroll
        for (int fj = 0; fj < 4; fj++) {
            int gcol = n0 + wc * 64 + fj * 16 + l16;
            #pragma unroll
            for (int r = 0; r < 4; r++) {
                int grow = grow_base + r;
                if (grow < 8000 && gcol < NC)
                    c[(size_t)grow * NC + gcol] = f2bf(acc[fi][fj][r]);
            }
        }
    }
}

// -------------------- Kernel 3: MFMA flash attention (swapped-operand) ------
// S^T = mfma(K, Q): lane owns one q-row (col=l16) and 8 j-values. Row-max =
// 7 lane-local fmax + 2 shuffle stages. Softmax denominator accumulates as a
// ones-row (d=20) of V^T through the PV MFMA (no sum-reduce).
#define KSTR 24
#define VSTR 520
#define PSTR 40
#define QSPLIT 2

__global__ __launch_bounds__(256) void k_attn4(
    const short* __restrict__ qkv,   // [8000][1200] bf16 = q|k|v
    const int* __restrict__ mask,    // [B,L]
    float* __restrict__ o)           // [8000][400]
{
    // Ksh [512][24] @0 ; VT [21][520] ; P [4][16][40] ; msk [512] bf16
    __shared__ short sh[12288 + 21 * VSTR + 4 * 16 * PSTR + 512];  // 52560 B
    short* VTb = sh + 12288;
    short* Pb  = VTb + 21 * VSTR;
    short* msk = Pb + 4 * 16 * PSTR;

    int part = blockIdx.x & (QSPLIT - 1);
    int bh = blockIdx.x >> 1;
    int b = bh / H, h = bh % H;
    int tid = threadIdx.x;
    int lane = tid & 63, w = tid >> 6;
    int quad = lane >> 4, l16 = lane & 15;

    // ---- stage K bf16 [512][24] via int loads: 12 short2 per row ----
    for (int u = tid; u < 512 * (KSTR / 2); u += 256) {
        int j = u / (KSTR / 2), t = u % (KSTR / 2);
        int v = 0;
        if (j < L && t < DH / 2)
            v = *(const int*)(qkv + (size_t)(b * L + j) * NC + 400 + h * DH + 2 * t);
        *(int*)&sh[j * KSTR + 2 * t] = v;
    }
    // ---- stage V^T rows 0..19: int load (d=2t,2t+1), two scalar LDS writes --
    for (int u = tid; u < L * (DH / 2); u += 256) {
        int j = u / (DH / 2), t = u % (DH / 2);
        int v = *(const int*)(qkv + (size_t)(b * L + j) * NC + 800 + h * DH + 2 * t);
        VTb[(2 * t) * VSTR + j]     = (short)(v & 0xffff);
        VTb[(2 * t + 1) * VSTR + j] = (short)((unsigned)v >> 16);
    }
    // ---- ones row d=20 (denominator trick) + bf16 mask; tails zeroed ----
    for (int j = tid; j < 512; j += 256) {
        VTb[20 * VSTR + j] = (j < L) ? f2bf(1.0f) : (short)0;
        msk[j] = (j < L && mask[(size_t)b * L + j] > 0) ? f2bf(1.0f) : (short)0;
    }
    for (int i = tid; i < DH * 12; i += 256) {   // zero V j-tail 500..511
        int d = i / 12, j = L + i % 12;
        VTb[d * VSTR + j] = 0;
    }
    __syncthreads();

    short* Pw = Pb + w * 16 * PSTR;       // per-wave private P^T buffer [16 q][32 j]
    short* pwr = Pw + l16 * PSTR;         // this lane's q-row
    const short* prd = Pw + l16 * PSTR + quad * 8;   // B-frag read base (16B-aligned)
    const short* kA  = sh + quad * 8;     // K A-frag col base (quad<3 only)
    const short* vA0 = VTb + l16 * VSTR;              // V^T rows 0..15
    int r1 = 16 + l16; if (r1 > 20) r1 = 20;          // clamp: garbage rows ignored
    const short* vA1 = VTb + r1 * VSTR;

    for (int qt = part * 16 + w; qt < part * 16 + 16; qt += 4) {
        // Q B-frag: 8-B short4 loads (base = 2400*row + 40h bytes, 8-B aligned)
        int qrow = qt * 16 + l16;
        const short* qp = qkv + (size_t)(b * L + (qrow < L ? qrow : 0)) * NC + h * DH;
        short8 aq = (short8)(short)0;
        if (quad < 2) {
            short4v a0 = *(const short4v*)(qp + quad * 8);
            short4v a1 = *(const short4v*)(qp + quad * 8 + 4);
            #pragma unroll
            for (int jj = 0; jj < 4; jj++) { aq[jj] = a0[jj]; aq[4 + jj] = a1[jj]; }
        } else if (quad == 2) {
            short4v a0 = *(const short4v*)(qp + 16);   // k = 16..19 valid
            #pragma unroll
            for (int jj = 0; jj < 4; jj++) aq[jj] = a0[jj];
        }
        // q-rows >= L read row 0: finite garbage, never stored (guard below)

        floatx4 O0 = (floatx4){0.f,0.f,0.f,0.f};
        floatx4 O1 = (floatx4){0.f,0.f,0.f,0.f};
        float mrun = -INFINITY;

        for (int jt = 0; jt < 16; jt++) {
            // K A-frags (quad3 -> zero regs; quad<3 reads [quad*8..+8) of 24-col rows)
            short8 ak0 = (short8)(short)0, ak1 = (short8)(short)0;
            if (quad < 3) {
                ak0 = *(const short8*)&kA[(jt * 32 + l16) * KSTR];
                ak1 = *(const short8*)&kA[(jt * 32 + 16 + l16) * KSTR];
            }
            floatx4 z = (floatx4){0.f,0.f,0.f,0.f};
            // S^T[j,q]: col=l16=q, row=quad*4+r=j (half0 / half1)
            floatx4 s0 = __builtin_amdgcn_mfma_f32_16x16x32_bf16(ak0, aq, z, 0, 0, 0);
            floatx4 s1 = __builtin_amdgcn_mfma_f32_16x16x32_bf16(ak1, aq, z, 0, 0, 0);

            short4v mk0 = *(const short4v*)&msk[jt * 32 + quad * 4];
            short4v mk1 = *(const short4v*)&msk[jt * 32 + 16 + quad * 4];
            #pragma unroll
            for (int r = 0; r < 4; r++) {
                s0[r] = (mk0[r] != 0) ? s0[r] : -1e9f;
                s1[r] = (mk1[r] != 0) ? s1[r] : -1e9f;
            }

            // tile row-max: 7 lane-local max + 2 cross-quad stages
            float mt = fmaxf(fmaxf(fmaxf(s0[0], s0[1]), fmaxf(s0[2], s0[3])),
                             fmaxf(fmaxf(s1[0], s1[1]), fmaxf(s1[2], s1[3])));
            mt = fmaxf(mt, __shfl_xor(mt, 16));
            mt = fmaxf(mt, __shfl_xor(mt, 32));

            if (!__all(mt <= mrun)) {
                float mnew = fmaxf(mrun, mt);
                float alpha = __expf(mrun - mnew);
                mrun = mnew;
                #pragma unroll
                for (int r = 0; r < 4; r++) { O0[r] *= alpha; O1[r] *= alpha; }
            }

            // P = exp(S - m); denominator accumulates via ones-row of V^T
            short4v pk0, pk1;
            #pragma unroll
            for (int r = 0; r < 4; r++) {
                pk0[r] = f2bf(__expf(s0[r] - mrun));
                pk1[r] = f2bf(__expf(s1[r] - mrun));
            }
            *(short4v*)&pwr[quad * 4]      = pk0;   // j = quad*4+r   (half 0)
            *(short4v*)&pwr[16 + quad * 4] = pk1;   // j = 16+quad*4+r (half 1)

            short8 ap  = *(const short8*)prd;                       // P^T B-frag
            short8 va0 = *(const short8*)&vA0[jt * 32 + quad * 8];  // V^T A-frag d=0..15
            short8 va1 = *(const short8*)&vA1[jt * 32 + quad * 8];  // d=16..20 (clamped)
            O0 = __builtin_amdgcn_mfma_f32_16x16x32_bf16(va0, ap, O0, 0, 0, 0);
            O1 = __builtin_amdgcn_mfma_f32_16x16x32_bf16(va1, ap, O1, 0, 0, 0);
        }

        // denominator lives at O^T row 20 = quad1, reg 0; broadcast per q-col
        float lsum = __shfl(O1[0], 16 + l16);
        float inv = 1.0f / lsum;
        int q = qt * 16 + l16;
        if (q < L) {
            float* op = o + (size_t)(b * L + q) * (H * DH) + h * DH;
            floatx4 v0;
            #pragma unroll
            for (int r = 0; r < 4; r++) v0[r] = O0[r] * inv;
            *(floatx4*)&op[quad * 4] = v0;           // d = quad*4..+3
            if (quad == 0) {
                floatx4 v1;
                #pragma unroll
                for (int r = 0; r < 4; r++) v1[r] = O1[r] * inv;
                *(floatx4*)&op[16] = v1;             // d = 16..19
            }
        }
    }
}

// -------------------- Kernel 4: LN1 + att_pool + LN2 (round-7 form) ---------
// 800 blocks (3.1/CU, balanced); fc1 reads xt as float4 (ds_read_b128).
__global__ __launch_bounds__(256) void k_pool(
    const float* __restrict__ o,
    const float* __restrict__ ln1g, const float* __restrict__ ln1b,
    const float* __restrict__ fc1w, const float* __restrict__ fc1b,
    const float* __restrict__ fc2w, const float* __restrict__ fc2b,
    const float* __restrict__ ln2g, const float* __restrict__ ln2b,
    const int* __restrict__ mask,   // [800,10]
    float* __restrict__ out)        // [800,400]
{
    __shared__ float xt[SLOTS][D];
    __shared__ float hv[SLOTS * ATT_H];
    __shared__ float es[SLOTS];
    __shared__ float red[8];

    int g = blockIdx.x;
    int tid = threadIdx.x;
    int lane = tid & 63, w = tid >> 6;

    const float* xg = o + (size_t)g * SLOTS * D;

    for (int s = w; s < SLOTS; s += 4) {
        const float* xr = xg + (size_t)s * D;
        float vbuf[7];
        float sum = 0.0f, sq = 0.0f;
        #pragma unroll
        for (int i = 0; i < 7; i++) {
            int d = lane + 64 * i;
            float v = (d < D) ? xr[d] : 0.0f;
            vbuf[i] = v; sum += v; sq += v * v;
        }
        #pragma unroll
        for (int off = 32; off > 0; off >>= 1) {
            sum += __shfl_xor(sum, off);
            sq  += __shfl_xor(sq, off);
        }
        float mean = sum / (float)D;
        float var = sq / (float)D - mean * mean;
        float rs = rsqrtf(var + EPS);
        #pragma unroll
        for (int i = 0; i < 7; i++) {
            int d = lane + 64 * i;
            if (d < D) xt[s][d] = (vbuf[i] - mean) * rs * ln1g[d] + ln1b[d];
        }
    }
    __syncthreads();

    {
        // fc1: float4 xt reads (ds_read_b128, 4x fewer LDS instrs);
        // accumulation order over d unchanged -> bit-identical results.
        int jh = tid & 127;
        int s0 = tid >> 7;
        float hs[5];
        #pragma unroll
        for (int jj = 0; jj < 5; jj++) hs[jj] = fc1b[jh];
        for (int d = 0; d < D; d += 4) {
            floatx4 xv0 = *(const floatx4*)&xt[s0 + 0][d];
            floatx4 xv1 = *(const floatx4*)&xt[s0 + 2][d];
            floatx4 xv2 = *(const floatx4*)&xt[s0 + 4][d];
            floatx4 xv3 = *(const floatx4*)&xt[s0 + 6][d];
            floatx4 xv4 = *(const floatx4*)&xt[s0 + 8][d];
            #pragma unroll
            for (int dd = 0; dd < 4; dd++) {
                float fw = fc1w[(size_t)(d + dd) * ATT_H + jh];
                hs[0] += xv0[dd] * fw;
                hs[1] += xv1[dd] * fw;
                hs[2] += xv2[dd] * fw;
                hs[3] += xv3[dd] * fw;
                hs[4] += xv4[dd] * fw;
            }
        }
        float f2 = fc2w[jh];
        #pragma unroll
        for (int jj = 0; jj < 5; jj++)
            hv[(s0 + 2 * jj) * ATT_H + jh] = tanhf(hs[jj]) * f2;
    }
    __syncthreads();

    for (int s = w; s < SLOTS; s += 4) {
        float p = hv[s * ATT_H + lane] + hv[s * ATT_H + lane + 64];
        #pragma unroll
        for (int off = 32; off > 0; off >>= 1) p += __shfl_xor(p, off);
        if (lane == 0) es[s] = p + fc2b[0];
    }
    __syncthreads();

    float ev[SLOTS];
    float emax = -INFINITY;
    #pragma unroll
    for (int s = 0; s < SLOTS; s++) {
        float e = (mask[(size_t)g * SLOTS + s] > 0) ? es[s] : -1e9f;
        ev[s] = e;
        if (e > emax) emax = e;
    }
    float esum = 0.0f;
    #pragma unroll
    for (int s = 0; s < SLOTS; s++) { ev[s] = __expf(ev[s] - emax); esum += ev[s]; }
    float einv = 1.0f / esum;

    int d0 = tid, d1 = tid + 256;
    float p0 = 0.0f, p1 = 0.0f;
    #pragma unroll
    for (int s = 0; s < SLOTS; s++) {
        p0 += ev[s] * xt[s][d0];
        if (d1 < D) p1 += ev[s] * xt[s][d1];
    }
    p0 *= einv; p1 *= einv;

    float sum = p0 + ((d1 < D) ? p1 : 0.0f);
    float sq  = p0 * p0 + ((d1 < D) ? p1 * p1 : 0.0f);
    #pragma unroll
    for (int off = 32; off > 0; off >>= 1) {
        sum += __shfl_xor(sum, off);
        sq  += __shfl_xor(sq, off);
    }
    if (lane == 0) { red[w] = sum; red[4 + w] = sq; }
    __syncthreads();
    float tsum = red[0] + red[1] + red[2] + red[3];
    float tsq  = red[4] + red[5] + red[6] + red[7];
    float mean = tsum / (float)D;
    float var = tsq / (float)D - mean * mean;
    float rs = rsqrtf(var + EPS);

    float* og = out + (size_t)g * D;
    og[d0] = (p0 - mean) * rs * ln2g[d0] + ln2b[d0];
    if (d1 < D) og[d1] = (p1 - mean) * rs * ln2g[d1] + ln2b[d1];
}

extern "C" void kernel_launch(void* const* d_in, const int* in_sizes, int n_in,
                              void* d_out, int out_size, void* d_ws, size_t ws_size,
                              hipStream_t stream) {
    const float* news  = (const float*)d_in[0];
    const float* table = (const float*)d_in[1];
    const float* Wq    = (const float*)d_in[2];
    const float* Wk    = (const float*)d_in[3];
    const float* Wv    = (const float*)d_in[4];
    const float* ln1g  = (const float*)d_in[5];
    const float* ln1b  = (const float*)d_in[6];
    const float* fc1w  = (const float*)d_in[7];
    const float* fc1b  = (const float*)d_in[8];
    const float* fc2w  = (const float*)d_in[9];
    const float* fc2b  = (const float*)d_in[10];
    const float* ln2g  = (const float*)d_in[11];
    const float* ln2b  = (const float*)d_in[12];
    const int* click   = (const int*)d_in[13];
    const int* nbrt    = (const int*)d_in[14];
    const int* mask    = (const int*)d_in[15];
    float* out = (float*)d_out;

    char* p = (char*)d_ws;
    short* xbf = (short*)p;  p += (size_t)8000 * XP * sizeof(short);   // 6.656 MB
    short* wT  = (short*)p;  p += (size_t)NC * XP * sizeof(short);     // 1.0 MB
    short* qkv = (short*)p;  p += (size_t)8000 * NC * sizeof(short);   // 19.2 MB
    float* ob  = (float*)p;                                            // 12.8 MB

    k_prep<<<dim3(B * NN + WTB), dim3(256), 0, stream>>>(
        news, table, click, nbrt, Wq, Wk, Wv, xbf, wT);
    k_qkv_mfma<<<dim3((8000 + BM - 1) / BM, (NC + BN - 1) / BN), dim3(256), 0, stream>>>(
        xbf, wT, qkv);
    k_attn4<<<dim3(B * H * QSPLIT), dim3(256), 0, stream>>>(qkv, mask, ob);
    k_pool<<<dim3(B * NN), dim3(256), 0, stream>>>(ob, ln1g, ln1b, fc1w, fc1b, fc2w, fc2b,
                                                   ln2g, ln2b, mask, out);
}